// Round 3
// baseline (208.796 us; speedup 1.0000x reference)
//
#include <hip/hip_runtime.h>
#include <stdint.h>

// Problem constants
#define T_DIM 512
#define B_DIM 128
#define DIN   512
#define H_DIM 1024
#define M_DIM (T_DIM * B_DIM)          // 65536
#define OUT_ELEMS 67108864             // M_DIM * H_DIM

typedef __attribute__((ext_vector_type(8))) short bf16x8;
typedef __attribute__((ext_vector_type(4))) float f32x4;
typedef unsigned short u16;

static __device__ __forceinline__ u16 f2bf(float f) {
    union { float f; uint32_t u; } v; v.f = f;
    uint32_t u = v.u;
    uint32_t r = (u + 0x7FFFu + ((u >> 16) & 1u)) >> 16;   // RNE
    return (u16)r;
}

typedef const __attribute__((address_space(1))) void GASV;
typedef __attribute__((address_space(3))) void LASV;
static __device__ __forceinline__ void gload_lds16(const void* g, void* l) {
    __builtin_amdgcn_global_load_lds((GASV*)g, (LASV*)l, 16, 0, 0);
}

// ---------------------------------------------------------------------------
// Kernel 1: convert x, W_in, W_h, hidden to bf16 (8 elems/thread);
//           copy hidden f32 to d_out tail.
// unit ranges: x [0,4194304) W_in [..,4259840) W_h [..,4390912) hid [..,4407296)
// ---------------------------------------------------------------------------
__global__ __launch_bounds__(256) void k_convert(
    const float* __restrict__ x, const float* __restrict__ W_in,
    const float* __restrict__ W_h, const float* __restrict__ hidden,
    u16* __restrict__ x_bf, u16* __restrict__ Win_bf,
    u16* __restrict__ Wh_bf, u16* __restrict__ hid_bf,
    float* __restrict__ out_hidden)
{
    int u = blockIdx.x * 256 + threadIdx.x;
    const float* src; u16* dst; int i;
    if (u < 4194304)      { i = u;           src = x;      dst = x_bf;   }
    else if (u < 4259840) { i = u - 4194304; src = W_in;   dst = Win_bf; }
    else if (u < 4390912) { i = u - 4259840; src = W_h;    dst = Wh_bf;  }
    else                  { i = u - 4390912; src = hidden; dst = hid_bf; }
    float4 v0 = reinterpret_cast<const float4*>(src)[2 * (size_t)i];
    float4 v1 = reinterpret_cast<const float4*>(src)[2 * (size_t)i + 1];
    union { bf16x8 v; u16 s[8]; } r;
    r.s[0] = f2bf(v0.x); r.s[1] = f2bf(v0.y);
    r.s[2] = f2bf(v0.z); r.s[3] = f2bf(v0.w);
    r.s[4] = f2bf(v1.x); r.s[5] = f2bf(v1.y);
    r.s[6] = f2bf(v1.z); r.s[7] = f2bf(v1.w);
    reinterpret_cast<bf16x8*>(dst)[i] = r.v;
    if (u >= 4390912) {   // second tuple output: hidden verbatim
        reinterpret_cast<float4*>(out_hidden)[2 * i]     = v0;
        reinterpret_cast<float4*>(out_hidden)[2 * i + 1] = v1;
    }
}

// ---------------------------------------------------------------------------
// Kernel 2: bias2[b][h] = hidden @ W_h^T + b_h + b_in   (128 x 1024, K=1024)
// (unchanged from round 2 — passed, off critical path)
// ---------------------------------------------------------------------------
__global__ __launch_bounds__(256, 2) void k_bias2(
    const u16* __restrict__ hid_bf, const u16* __restrict__ Wh_bf,
    const float* __restrict__ b_in, const float* __restrict__ b_h,
    float* __restrict__ bias2)
{
    __shared__ alignas(16) char lds[16384];     // A: [0,8192) B: [8192,16384)
    const int tid = threadIdx.x;
    const int mt = blockIdx.x & 1, nt = blockIdx.x >> 1;   // 2 x 16 tiles
    const int m0 = mt * 64, n0 = nt * 64;
    const int l = tid & 63, w = tid >> 6;
    const int wm = w >> 1, wn = w & 1;
    const int r = l & 15, q = l >> 4;

    f32x4 acc[2][2] = {};

    for (int kb = 0; kb < 1024; kb += 64) {
        __syncthreads();
        #pragma unroll
        for (int i = 0; i < 2; ++i) {
            int idx = tid + i * 256;            // 0..511 : 64 rows x 8 chunks
            int row = idx >> 3, koff = (idx & 7) * 8;
            int off = (row * 128 + koff * 2) ^ ((row & 7) << 4);
            bf16x8 av = *reinterpret_cast<const bf16x8*>(&hid_bf[(m0 + row) * 1024 + kb + koff]);
            *reinterpret_cast<bf16x8*>(&lds[off]) = av;
            bf16x8 bv = *reinterpret_cast<const bf16x8*>(&Wh_bf[(n0 + row) * 1024 + kb + koff]);
            *reinterpret_cast<bf16x8*>(&lds[8192 + off]) = bv;
        }
        __syncthreads();
        #pragma unroll
        for (int kk = 0; kk < 2; ++kk) {
            bf16x8 a[2], b[2];
            #pragma unroll
            for (int mi = 0; mi < 2; ++mi) {
                int row = wm * 32 + mi * 16 + r;
                int off = (row * 128 + kk * 64 + q * 16) ^ ((row & 7) << 4);
                a[mi] = *reinterpret_cast<const bf16x8*>(&lds[off]);
            }
            #pragma unroll
            for (int ni = 0; ni < 2; ++ni) {
                int row = wn * 32 + ni * 16 + r;
                int off = 8192 + ((row * 128 + kk * 64 + q * 16) ^ ((row & 7) << 4));
                b[ni] = *reinterpret_cast<const bf16x8*>(&lds[off]);
            }
            #pragma unroll
            for (int mi = 0; mi < 2; ++mi)
                #pragma unroll
                for (int ni = 0; ni < 2; ++ni)
                    acc[mi][ni] = __builtin_amdgcn_mfma_f32_16x16x32_bf16(
                        a[mi], b[ni], acc[mi][ni], 0, 0, 0);
        }
    }
    #pragma unroll
    for (int mi = 0; mi < 2; ++mi)
        #pragma unroll
        for (int ni = 0; ni < 2; ++ni)
            #pragma unroll
            for (int reg = 0; reg < 4; ++reg) {
                int brow = m0 + wm * 32 + mi * 16 + q * 4 + reg;
                int col  = n0 + wn * 32 + ni * 16 + r;
                bias2[brow * 1024 + col] = acc[mi][ni][reg] + b_in[col] + b_h[col];
            }
}

// ---------------------------------------------------------------------------
// Kernel 3: main GEMM, m97-classic template.
//   Both operands bf16 via global_load_lds(16B), single LDS buffer (32 KB ->
//   4 blocks/CU), __syncthreads drains. XOR-swizzled LDS via pre-swizzled
//   global source (G21). Operand-swapped MFMA -> float4 epilogue.
// ---------------------------------------------------------------------------
__global__ __launch_bounds__(256, 4) void k_main(
    const u16* __restrict__ x_bf,         // [65536][512] bf16
    const u16* __restrict__ Win_bf,       // [1024][512] bf16
    const float* __restrict__ bias2,      // [128][1024]
    const float* __restrict__ hidden,     // [128][1024]
    float* __restrict__ out)              // [65536][1024]
{
    __shared__ alignas(16) char ldsA[16384];   // 128 rows x 64 bf16, swizzled
    __shared__ alignas(16) char ldsB[16384];

    const int tid = threadIdx.x;
    const int bid = (int)blockIdx.x;
    // XCD-bijective swizzle: 4096 % 8 == 0; XCD x owns wgid [x*512,(x+1)*512)
    const int wgid = (bid & 7) * 512 + (bid >> 3);
    const int nt = wgid & 7, mt = wgid >> 3;
    const int m0 = mt * 128, n0 = nt * 128;
    const int l = tid & 63, w = tid >> 6;
    const int wm = w >> 1, wn = w & 1;          // 2x2 waves, 64x64 each
    const int r = l & 15, q = l >> 4;

    // staging: wave w stages segs w*4..w*4+3; seg = 8 rows x 8 chunks(16B)
    const int rs = l >> 3;                      // row within segment (=row&7)
    const int ck = (l & 7) ^ rs;                // pre-swizzled source chunk

    f32x4 acc[4][4] = {};

    for (int k = 0; k < 8; ++k) {
        #pragma unroll
        for (int j = 0; j < 4; ++j) {
            const int seg = w * 4 + j;
            const int row = seg * 8 + rs;
            gload_lds16(&x_bf[(size_t)(m0 + row) * 512 + k * 64 + ck * 8],
                        &ldsA[seg * 1024]);
            gload_lds16(&Win_bf[(size_t)(n0 + row) * 512 + k * 64 + ck * 8],
                        &ldsB[seg * 1024]);
        }
        __syncthreads();   // drains vmcnt(0): tiles resident

        #pragma unroll
        for (int kk = 0; kk < 2; ++kk) {
            bf16x8 a[4], b[4];
            #pragma unroll
            for (int mi = 0; mi < 4; ++mi) {
                int row = wm * 64 + mi * 16 + r;
                int off = (row * 128 + kk * 64 + q * 16) ^ ((row & 7) << 4);
                a[mi] = *reinterpret_cast<const bf16x8*>(&ldsA[off]);
            }
            #pragma unroll
            for (int ni = 0; ni < 4; ++ni) {
                int row = wn * 64 + ni * 16 + r;
                int off = (row * 128 + kk * 64 + q * 16) ^ ((row & 7) << 4);
                b[ni] = *reinterpret_cast<const bf16x8*>(&ldsB[off]);
            }
            // swapped operands: D-row = n (B rows), D-col = m (A rows)
            // => lane (q,r): m = base_m + r, regs = 4 consecutive n
            #pragma unroll
            for (int mi = 0; mi < 4; ++mi)
                #pragma unroll
                for (int ni = 0; ni < 4; ++ni)
                    acc[mi][ni] = __builtin_amdgcn_mfma_f32_16x16x32_bf16(
                        b[ni], a[mi], acc[mi][ni], 0, 0, 0);
        }
        __syncthreads();   // protect LDS before next K-step's staging
    }

    // ---- epilogue: out = 0.9*hidden + 0.1*relu(acc + bias2), float4-wide ----
    #pragma unroll
    for (int mi = 0; mi < 4; ++mi) {
        const int m = m0 + wm * 64 + mi * 16 + r;
        const int b = m & 127;                  // m = t*128 + b
        #pragma unroll
        for (int ni = 0; ni < 4; ++ni) {
            const int n = n0 + wn * 64 + ni * 16 + q * 4;
            float4 bb = *reinterpret_cast<const float4*>(&bias2[b * 1024 + n]);
            float4 hh = *reinterpret_cast<const float4*>(&hidden[b * 1024 + n]);
            f32x4 v = acc[mi][ni];
            float4 o;
            o.x = 0.9f * hh.x + 0.1f * fmaxf(v[0] + bb.x, 0.0f);
            o.y = 0.9f * hh.y + 0.1f * fmaxf(v[1] + bb.y, 0.0f);
            o.z = 0.9f * hh.z + 0.1f * fmaxf(v[2] + bb.z, 0.0f);
            o.w = 0.9f * hh.w + 0.1f * fmaxf(v[3] + bb.w, 0.0f);
            *reinterpret_cast<float4*>(&out[(size_t)m * 1024 + n]) = o;
        }
    }
}

// ---------------------------------------------------------------------------
extern "C" void kernel_launch(void* const* d_in, const int* in_sizes, int n_in,
                              void* d_out, int out_size, void* d_ws, size_t ws_size,
                              hipStream_t stream) {
    const float* x      = (const float*)d_in[0];
    const float* hidden = (const float*)d_in[1];
    const float* W_in   = (const float*)d_in[2];
    const float* b_in   = (const float*)d_in[3];
    const float* W_h    = (const float*)d_in[4];
    const float* b_h    = (const float*)d_in[5];
    float* out = (float*)d_out;

    char* ws = (char*)d_ws;                    // needs ~71 MiB of scratch
    u16*   x_bf   = (u16*)  (ws + 0);          // 64 MiB
    u16*   Win_bf = (u16*)  (ws + 67108864);   // 1 MiB
    u16*   Wh_bf  = (u16*)  (ws + 68157440);   // 2 MiB
    u16*   hid_bf = (u16*)  (ws + 70254592);   // 256 KiB
    float* bias2  = (float*)(ws + 70516736);   // 512 KiB

    float* out_hidden = out + OUT_ELEMS;       // tuple output 1: hidden

    k_convert<<<17216, 256, 0, stream>>>(x, W_in, W_h, hidden,
                                         x_bf, Win_bf, Wh_bf, hid_bf, out_hidden);
    k_bias2<<<32, 256, 0, stream>>>(hid_bf, Wh_bf, b_in, b_h, bias2);
    k_main<<<4096, 256, 0, stream>>>(x_bf, Win_bf, bias2, hidden, out);
}